// Round 9
// baseline (38.033 us; speedup 1.0000x reference)
//
#include <hip/hip_runtime.h>
#include <math.h>

typedef float f32x4 __attribute__((ext_vector_type(4)));
typedef float f32x2 __attribute__((ext_vector_type(2)));

#define DOT4(A, B) ((A)[0]*(B)[0] + (A)[1]*(B)[1] + (A)[2]*(B)[2] + (A)[3]*(B)[3])

// DP shape (R8) + zero divergent global access:
//  - 8 images/block staged to LDS via coalesced f32x4 loads; taps read from LDS
//  - Wc1 reg-staged (coalesced) before the recurrence, LDS-written after it
//    (latency hides under compute), classifier reads it from LDS stride-132
// 8 samples/block, 2048 blocks, 256 threads; LDS ~60 KB -> 2 blocks/CU.
__global__ __launch_bounds__(256) void mnist_dp4(
    const float* __restrict__ img, const float* __restrict__ Wff,
    const float* __restrict__ Wfb, const float* __restrict__ Wvel,
    const float* __restrict__ Wc1, const float* __restrict__ bc1,
    const float* __restrict__ Wc2, const float* __restrict__ bc2,
    float* __restrict__ out) {
  __shared__ float A[64 * 132];      // phase1: imgL[6272] ; phase2: Wc1L[64][132]
  __shared__ float WffL[32 * 36];
  __shared__ float WfbL[32 * 36];
  __shared__ float Bu[2048];         // phase1: Mds[32*36] ; phase2: L1 partials
  __shared__ float snL[8 * 36];
  __shared__ float tdL[8 * 36];
  __shared__ float r6L[8 * 36];
  __shared__ float ftL[8 * 132];
  __shared__ float hLd[8 * 68];

  const int t = threadIdx.x;
  const int s = t >> 5, p = t & 31;       // sample-in-block, unit
  const int sg = blockIdx.x * 8 + s;

  // ---- coalesced image stage: 8 images = 1568 f32x4 ----
  const float* gimg = img + (size_t)blockIdx.x * 8 * 784;
  f32x4 i0 = *(const f32x4*)(gimg + (t)          * 4);
  f32x4 i1 = *(const f32x4*)(gimg + (t + 256)    * 4);
  f32x4 i2 = *(const f32x4*)(gimg + (t + 512)    * 4);
  f32x4 i3 = *(const f32x4*)(gimg + (t + 768)    * 4);
  f32x4 i4 = *(const f32x4*)(gimg + (t + 1024)   * 4);
  f32x4 i5 = *(const f32x4*)(gimg + (t + 1280)   * 4);
  f32x4 i6 = {0.f, 0.f, 0.f, 0.f};
  if (t < 32) i6 = *(const f32x4*)(gimg + (t + 1536) * 4);

  // ---- small weights (coalesced) ----
  const int rj = t >> 3, c4 = (t & 7) * 4;
  const f32x4 wf4 = *(const f32x4*)(Wff + rj * 32 + c4);
  const f32x4 wb4 = *(const f32x4*)(Wfb + rj * 32 + c4);
  const float2 wvp = ((const float2*)Wvel)[p];

  *(f32x4*)(WffL + rj * 36 + c4) = wf4;
  *(f32x4*)(WfbL + rj * 36 + c4) = wb4;
  *(f32x4*)(A + (t)          * 4) = i0;
  *(f32x4*)(A + (t + 256)    * 4) = i1;
  *(f32x4*)(A + (t + 512)    * 4) = i2;
  *(f32x4*)(A + (t + 768)    * 4) = i3;
  *(f32x4*)(A + (t + 1024)   * 4) = i4;
  *(f32x4*)(A + (t + 1280)   * 4) = i5;
  if (t < 32) *(f32x4*)(A + (t + 1536) * 4) = i6;
  __syncthreads();

  // ---- taps from LDS (pos in [11.75,771.25], never clipped; hi = lo+1) ----
  const float pos = 24.5f * (float)p + 11.75f;
  const int lo = (int)pos;
  const float w = pos - (float)lo;
  const int ta = (lo % 28) * 28 + lo / 28;
  const int tb = ((lo + 1) % 28) * 28 + (lo + 1) / 28;
  const float* ims = A + s * 784;
  const float a0 = ims[lo], a1 = ims[lo + 1];
  const float c0 = ims[ta], c1 = ims[tb];
  const float sv = (a0 + (a1 - a0) * w) * 80.0f;
  const float tv = (c0 + (c1 - c0) * w) * 40.0f;
  snL[s * 36 + p] = sv;
  tdL[s * 36 + p] = tv;

  // ---- cooperative M = Wff @ Wfb -> Bu ----
  {
    const int i = t >> 3, k0 = (t & 7) * 4;
    float m0 = 0.f, m1 = 0.f, m2 = 0.f, m3 = 0.f;
#pragma unroll
    for (int j = 0; j < 32; ++j) {
      const float a = WffL[i * 36 + j];
      const f32x4 w4 = *(const f32x4*)(WfbL + j * 36 + k0);
      m0 += a * w4[0]; m1 += a * w4[1]; m2 += a * w4[2]; m3 += a * w4[3];
    }
    f32x4 m = {m0, m1, m2, m3};
    *(f32x4*)(Bu + i * 36 + k0) = m;
  }
  __syncthreads();          // taps read, M built; A is DEAD after this point

  // ---- own M row into 8 NAMED f32x4 regs ----
  const float* Mrow = Bu + p * 36;
  const f32x4 M0 = *(const f32x4*)(Mrow +  0);
  const f32x4 M1 = *(const f32x4*)(Mrow +  4);
  const f32x4 M2 = *(const f32x4*)(Mrow +  8);
  const f32x4 M3 = *(const f32x4*)(Mrow + 12);
  const f32x4 M4 = *(const f32x4*)(Mrow + 16);
  const f32x4 M5 = *(const f32x4*)(Mrow + 20);
  const f32x4 M6 = *(const f32x4*)(Mrow + 24);
  const f32x4 M7 = *(const f32x4*)(Mrow + 28);

  // ---- sff = Wff[p]·sens ; yfb = relu(Wfb[p]·td) ----
  float sf = 0.f, yb = 0.f;
#pragma unroll
  for (int jb = 0; jb < 8; ++jb) {
    const f32x4 s4 = *(const f32x4*)(snL + s * 36 + jb * 4);
    const f32x4 t4 = *(const f32x4*)(tdL + s * 36 + jb * 4);
    const f32x4 f4 = *(const f32x4*)(WffL + p * 36 + jb * 4);
    const f32x4 g4 = *(const f32x4*)(WfbL + p * 36 + jb * 4);
    sf += DOT4(f4, s4);
    yb += DOT4(g4, t4);
  }
  yb = fmaxf(yb, 0.f);

  // ---- issue coalesced Wc1 loads NOW; they fly during the recurrence ----
  f32x4 cw0 = *(const f32x4*)(Wc1 + (t)          * 4);
  f32x4 cw1 = *(const f32x4*)(Wc1 + (t + 256)    * 4);
  f32x4 cw2 = *(const f32x4*)(Wc1 + (t + 512)    * 4);
  f32x4 cw3 = *(const f32x4*)(Wc1 + (t + 768)    * 4);
  f32x4 cw4 = *(const f32x4*)(Wc1 + (t + 1024)   * 4);
  f32x4 cw5 = *(const f32x4*)(Wc1 + (t + 1280)   * 4);
  f32x4 cw6 = *(const f32x4*)(Wc1 + (t + 1536)   * 4);
  f32x4 cw7 = *(const f32x4*)(Wc1 + (t + 1792)   * 4);

  // ---- recurrence: y = relu(sff - M·r6); r6 += 0.1*(-r6 + y + yfb + vin) ----
  float r = 0.f, y = 0.f, e = 0.f;
  const float VX[3] = {0.2f, 0.0f, 0.15f};
  const float VY[3] = {0.0f, 0.2f, 0.15f};
#pragma unroll
  for (int v = 0; v < 3; ++v) {
    const float vi = wvp.x * VX[v] + wvp.y * VY[v];
#pragma unroll
    for (int st = 0; st < 3; ++st) {
      r6L[s * 36 + p] = r;
      __builtin_amdgcn_wave_barrier();
      const f32x4 r40 = *(const f32x4*)(r6L + s * 36 +  0);
      const f32x4 r41 = *(const f32x4*)(r6L + s * 36 +  4);
      const f32x4 r42 = *(const f32x4*)(r6L + s * 36 +  8);
      const f32x4 r43 = *(const f32x4*)(r6L + s * 36 + 12);
      const f32x4 r44 = *(const f32x4*)(r6L + s * 36 + 16);
      const f32x4 r45 = *(const f32x4*)(r6L + s * 36 + 20);
      const f32x4 r46 = *(const f32x4*)(r6L + s * 36 + 24);
      const f32x4 r47 = *(const f32x4*)(r6L + s * 36 + 28);
      float accA = sf - DOT4(M0, r40) - DOT4(M2, r42) - DOT4(M4, r44) - DOT4(M6, r46);
      float accB =      DOT4(M1, r41) + DOT4(M3, r43) + DOT4(M5, r45) + DOT4(M7, r47);
      if (v == 2 && st == 2) {
        float pa = 0.f, pb = 0.f;
        const float* gr = WfbL + p * 36;
        pa += DOT4((*(const f32x4*)(gr +  0)), r40);
        pb += DOT4((*(const f32x4*)(gr +  4)), r41);
        pa += DOT4((*(const f32x4*)(gr +  8)), r42);
        pb += DOT4((*(const f32x4*)(gr + 12)), r43);
        pa += DOT4((*(const f32x4*)(gr + 16)), r44);
        pb += DOT4((*(const f32x4*)(gr + 20)), r45);
        pa += DOT4((*(const f32x4*)(gr + 24)), r46);
        pb += DOT4((*(const f32x4*)(gr + 28)), r47);
        e = fabsf(sv - (pa + pb));
      }
      __builtin_amdgcn_wave_barrier();
      y = fmaxf(accA - accB, 0.f);
      r += 0.1f * (y - r + yb + vi);
    }
  }

  // ---- write Wc1 tile to A (stride 132) + features; then sync ----
  {
    const int u0 = t;
    *(f32x4*)(A + (u0 >> 5) * 132 + (u0 & 31) * 4)          = cw0;
    *(f32x4*)(A + ((u0 + 256)  >> 5) * 132 + (u0 & 31) * 4) = cw1;
    *(f32x4*)(A + ((u0 + 512)  >> 5) * 132 + (u0 & 31) * 4) = cw2;
    *(f32x4*)(A + ((u0 + 768)  >> 5) * 132 + (u0 & 31) * 4) = cw3;
    *(f32x4*)(A + ((u0 + 1024) >> 5) * 132 + (u0 & 31) * 4) = cw4;
    *(f32x4*)(A + ((u0 + 1280) >> 5) * 132 + (u0 & 31) * 4) = cw5;
    *(f32x4*)(A + ((u0 + 1536) >> 5) * 132 + (u0 & 31) * 4) = cw6;
    *(f32x4*)(A + ((u0 + 1792) >> 5) * 132 + (u0 & 31) * 4) = cw7;
  }
  ftL[s * 132 +      p] = y;
  ftL[s * 132 + 32 + p] = yb;
  ftL[s * 132 + 64 + p] = r;
  ftL[s * 132 + 96 + p] = e;
  __syncthreads();

  // ---- classifier L1 pass 1: wave q = f-quarter, lane o = h-unit ----
  {
    const int q = t >> 6, o = t & 63;
    const float* wrow = A + o * 132 + q * 32;
    float acc[8] = {0.f, 0.f, 0.f, 0.f, 0.f, 0.f, 0.f, 0.f};
#pragma unroll
    for (int fb = 0; fb < 8; ++fb) {
      const f32x4 w4 = *(const f32x4*)(wrow + fb * 4);
#pragma unroll
      for (int ss = 0; ss < 8; ++ss) {
        const f32x4 f4 = *(const f32x4*)(ftL + ss * 132 + q * 32 + fb * 4); // broadcast
        acc[ss] += DOT4(w4, f4);
      }
    }
#pragma unroll
    for (int ss = 0; ss < 8; ++ss)
      Bu[q * 512 + ss * 64 + o] = acc[ss];
  }
  __syncthreads();

  // ---- classifier L1 pass 2: reduce partials, bias + gelu ----
  {
    const int o = t & 63, s2 = t >> 6;
    const float b = bc1[o];
    const float hA = b + Bu[s2 * 64 + o]        + Bu[512 + s2 * 64 + o]
                       + Bu[1024 + s2 * 64 + o] + Bu[1536 + s2 * 64 + o];
    const int s3 = s2 + 4;
    const float hB = b + Bu[s3 * 64 + o]        + Bu[512 + s3 * 64 + o]
                       + Bu[1024 + s3 * 64 + o] + Bu[1536 + s3 * 64 + o];
    hLd[s2 * 68 + o] = 0.5f * hA * (1.0f + erff(hA * 0.70710678118654752f));
    hLd[s3 * 68 + o] = 0.5f * hB * (1.0f + erff(hB * 0.70710678118654752f));
  }
  __syncthreads();

  // ---- classifier L2: logits (Wc2 is 2.5 KB, L1-resident) ----
  if (p < 10) {
    float acc = bc2[p];
    const float* w2 = Wc2 + (size_t)p * 64;
#pragma unroll
    for (int hb = 0; hb < 16; ++hb) {
      const f32x4 h4 = *(const f32x4*)(hLd + s * 68 + hb * 4);  // broadcast
      const f32x4 w4 = *(const f32x4*)(w2 + hb * 4);
      acc += DOT4(w4, h4);
    }
    out[(size_t)sg * 10 + p] = acc;
  }
}

extern "C" void kernel_launch(void* const* d_in, const int* in_sizes, int n_in,
                              void* d_out, int out_size, void* d_ws, size_t ws_size,
                              hipStream_t stream) {
  const float* img  = (const float*)d_in[0];
  const float* Wff  = (const float*)d_in[1];
  const float* Wfb  = (const float*)d_in[2];
  const float* Wvel = (const float*)d_in[3];
  const float* Wc1  = (const float*)d_in[4];
  const float* bc1  = (const float*)d_in[5];
  const float* Wc2  = (const float*)d_in[6];
  const float* bc2  = (const float*)d_in[7];
  float* out = (float*)d_out;
  const int B = in_sizes[0] / 784;     // 16384
  const int grid = B / 8;              // 2048 blocks, 8 samples each
  hipLaunchKernelGGL(mnist_dp4, dim3(grid), dim3(256), 0, stream,
                     img, Wff, Wfb, Wvel, Wc1, bc1, Wc2, bc2, out);
}